// Round 2
// baseline (376.013 us; speedup 1.0000x reference)
//
#include <hip/hip_runtime.h>

// CommunityGNN: 2× GCNConv + contrastive loss, N=12000, E=384000, F_IN=128, H=64.
// Key algebra: sim.sum() == ||sum_i z_i||^2  (never materialize N×N sim);
// pos_sum = sum over UNIQUE edges of z[s]·z[d]  (pos_mask .at[].set() dedupes).

constexpr int HDIM = 64;
constexpr int FIN = 128;
constexpr unsigned HASH_BITS = 20;
constexpr unsigned HASH_SIZE = 1u << HASH_BITS;   // 1M slots, load factor ~0.37
constexpr unsigned HASH_MASK = HASH_SIZE - 1u;

__global__ void count_kernel(const int* __restrict__ dst, int* __restrict__ cnt, int E) {
  int e = blockIdx.x * blockDim.x + threadIdx.x;
  if (e < E) atomicAdd(&cnt[dst[e]], 1);
}

__global__ void dinv_kernel(const int* __restrict__ cnt, float* __restrict__ dinv, int n) {
  int v = blockIdx.x * blockDim.x + threadIdx.x;
  if (v < n) dinv[v] = rsqrtf((float)(cnt[v] + 1));  // +1 = self loop
}

// Exclusive prefix sum of cnt[0..n) -> off[0..n]. Single block of 1024 threads,
// shuffle-based (3 barriers per 1024-chunk instead of 20).
__global__ void scan_kernel(const int* __restrict__ cnt, int* __restrict__ off, int n) {
  __shared__ int wsum[16];
  __shared__ int carry_s;
  const int tid = threadIdx.x, lane = tid & 63, wv = tid >> 6;
  if (tid == 0) carry_s = 0;
  __syncthreads();
  const int nchunk = (n + 1023) / 1024;
  for (int chunk = 0; chunk < nchunk; ++chunk) {
    int i = chunk * 1024 + tid;
    int c = carry_s;
    int v = (i < n) ? cnt[i] : 0;
    int x = v;  // inclusive wave scan
#pragma unroll
    for (int o = 1; o < 64; o <<= 1) { int t = __shfl_up(x, o, 64); if (lane >= o) x += t; }
    if (lane == 63) wsum[wv] = x;
    __syncthreads();
    if (wv == 0) {
      int t = (lane < 16) ? wsum[lane] : 0;
#pragma unroll
      for (int o = 1; o < 16; o <<= 1) { int u = __shfl_up(t, o, 64); if (lane >= o) t += u; }
      if (lane < 16) wsum[lane] = t;
    }
    __syncthreads();
    int incl = x + (wv ? wsum[wv - 1] : 0) + c;
    if (i < n) off[i] = incl - v;             // exclusive
    if (tid == 1023) carry_s = c + wsum[15];  // chunk total
    __syncthreads();
  }
  if (tid == 0) off[n] = carry_s;
}

__global__ void fill_kernel(const int* __restrict__ src, const int* __restrict__ dst,
                            const int* __restrict__ off, int* __restrict__ fill,
                            int* __restrict__ csr, int E) {
  int e = blockIdx.x * blockDim.x + threadIdx.x;
  if (e < E) {
    int d = dst[e];
    int pos = off[d] + atomicAdd(&fill[d], 1);
    csr[pos] = src[e];
  }
}

// out[n,64] = A[n,K] @ W[K,64]. Block = 256 threads = 4 rows × 64 cols; W in LDS.
// LDS access w[k*64+col]: lane i -> bank i%32, 2-way aliasing = free.
template <int K>
__global__ void gemm_kernel(const float* __restrict__ A, const float* __restrict__ W,
                            float* __restrict__ out, int n) {
  __shared__ float w[K * HDIM];
  for (int i = threadIdx.x; i < K * HDIM; i += 256) w[i] = W[i];
  __syncthreads();
  int col = threadIdx.x & 63;
  int row = blockIdx.x * 4 + (threadIdx.x >> 6);
  if (row >= n) return;
  const float* a = A + (size_t)row * K;
  float acc = 0.f;
#pragma unroll
  for (int k = 0; k < K; ++k) acc = fmaf(a[k], w[k * HDIM + col], acc);
  out[(size_t)row * HDIM + col] = acc;
}

// One wave per node, lane = feature. acc = sum_{s in N(v)} hin[s]*dinv[s]*dinv[v] + self.
__global__ void conv_relu_kernel(const float* __restrict__ hin, const int* __restrict__ csr,
                                 const int* __restrict__ off, const float* __restrict__ dinv,
                                 const float* __restrict__ bias, float* __restrict__ hout, int n) {
  int wid = (blockIdx.x * blockDim.x + threadIdx.x) >> 6;
  int lane = threadIdx.x & 63;
  if (wid >= n) return;
  float dv = dinv[wid];
  float acc = hin[(size_t)wid * HDIM + lane] * (dv * dv);  // self loop
  int s1 = off[wid + 1];
  for (int i = off[wid]; i < s1; ++i) {
    int s = csr[i];
    acc = fmaf(hin[(size_t)s * HDIM + lane], dinv[s] * dv, acc);
  }
  acc += bias[lane];
  hout[(size_t)wid * HDIM + lane] = fmaxf(acc, 0.f);
}

// conv2 + bias + row-normalize + column-sum (for ||sum z||^2), all fused.
__global__ void conv_norm_kernel(const float* __restrict__ hin, const int* __restrict__ csr,
                                 const int* __restrict__ off, const float* __restrict__ dinv,
                                 const float* __restrict__ bias, float* __restrict__ z,
                                 double* __restrict__ sumz, int n) {
  __shared__ double lds[4][HDIM];
  int wv = threadIdx.x >> 6, lane = threadIdx.x & 63;
  int wid = blockIdx.x * 4 + wv;
  double zv = 0.0;
  if (wid < n) {
    float dv = dinv[wid];
    float acc = hin[(size_t)wid * HDIM + lane] * (dv * dv);
    int s1 = off[wid + 1];
    for (int i = off[wid]; i < s1; ++i) {
      int s = csr[i];
      acc = fmaf(hin[(size_t)s * HDIM + lane], dinv[s] * dv, acc);
    }
    acc += bias[lane];
    float ss = acc * acc;
#pragma unroll
    for (int o = 32; o; o >>= 1) ss += __shfl_xor(ss, o, 64);
    float zf = acc / fmaxf(sqrtf(ss), 1e-12f);
    z[(size_t)wid * HDIM + lane] = zf;
    zv = (double)zf;
  }
  lds[wv][lane] = zv;
  __syncthreads();
  if (wv == 0) {
    double t = lds[0][lane] + lds[1][lane] + lds[2][lane] + lds[3][lane];
    atomicAdd(&sumz[lane], t);
  }
}

// Unique-edge dot products. Each wave owns a batch of 64 edges: all 64 lanes
// hash-probe in parallel, ballot the unique ones, then stream coalesced z-row
// pairs with per-lane double accumulation (no per-edge reduce needed).
__global__ void pos_kernel(const int* __restrict__ src, const int* __restrict__ dst,
                           const float* __restrict__ z, unsigned* __restrict__ hash,
                           double* __restrict__ pos_sum, unsigned long long* __restrict__ pos_cnt,
                           int E, int n) {
  int lane = threadIdx.x & 63;
  int wid = (blockIdx.x * blockDim.x + threadIdx.x) >> 6;
  int nw = (gridDim.x * blockDim.x) >> 6;
  double acc = 0.0;
  unsigned long long lcnt = 0;
  for (int base = wid * 64; base < E; base += nw * 64) {
    int e = base + lane;
    int s = 0, d = 0, isnew = 0;
    if (e < E) {
      s = src[e]; d = dst[e];
      unsigned key = (unsigned)s * (unsigned)n + (unsigned)d + 1u;  // nonzero, < 2^31
      unsigned hsh = (key * 2654435761u) & HASH_MASK;
      for (;;) {
        unsigned prev = atomicCAS(&hash[hsh], 0u, key);
        if (prev == 0u) { isnew = 1; break; }
        if (prev == key) break;
        hsh = (hsh + 1u) & HASH_MASK;
      }
    }
    unsigned long long mask = __ballot(isnew != 0);
    if (lane == 0) lcnt += (unsigned long long)__popcll(mask);
    while (mask) {
      int b = __ffsll((unsigned long long)mask) - 1;
      mask &= mask - 1;
      int ss = __shfl(s, b, 64), dd = __shfl(d, b, 64);
      float p = z[(size_t)ss * HDIM + lane] * z[(size_t)dd * HDIM + lane];
      acc += (double)p;
    }
  }
#pragma unroll
  for (int o = 32; o; o >>= 1) acc += __shfl_xor(acc, o, 64);
  if (lane == 0) {
    if (acc != 0.0) atomicAdd(pos_sum, acc);
    if (lcnt) atomicAdd(pos_cnt, lcnt);
  }
}

__global__ void finalize_kernel(const double* __restrict__ sumz, const double* __restrict__ pos_sum,
                                const unsigned long long* __restrict__ pos_cnt,
                                float* __restrict__ out, int n) {
  if (threadIdx.x == 0 && blockIdx.x == 0) {
    double tot = 0.0;
    for (int k = 0; k < HDIM; ++k) { double s = sumz[k]; tot += s * s; }
    double ps = *pos_sum;
    double pc = (double)*pos_cnt;
    double n2 = (double)n * (double)n;
    out[0] = (float)(-(ps / pc) + (tot - ps) / (n2 - pc));
  }
}

extern "C" void kernel_launch(void* const* d_in, const int* in_sizes, int n_in,
                              void* d_out, int out_size, void* d_ws, size_t ws_size,
                              hipStream_t stream) {
  (void)n_in; (void)out_size; (void)ws_size;
  const float* x  = (const float*)d_in[0];
  const int* eidx = (const int*)d_in[1];
  const float* W1 = (const float*)d_in[2];
  const float* b1 = (const float*)d_in[3];
  const float* W2 = (const float*)d_in[4];
  const float* b2 = (const float*)d_in[5];
  float* out = (float*)d_out;

  const int N = in_sizes[0] / FIN;   // 12000
  const int E = in_sizes[1] / 2;     // 384000
  const int* src = eidx;
  const int* dst = eidx + E;

  char* p = (char*)d_ws;
  auto alloc = [&](size_t bytes) -> void* {
    void* r = (void*)p;
    p += (bytes + 255) & ~(size_t)255;
    return r;
  };
  // --- zeroed region (one contiguous memset) ---
  unsigned* hash = (unsigned*)alloc(sizeof(unsigned) * HASH_SIZE);  // 4 MB
  int* cnt  = (int*)alloc(sizeof(int) * N);
  int* fill = (int*)alloc(sizeof(int) * N);
  double* sumz = (double*)alloc(sizeof(double) * HDIM);
  double* pos_sum = (double*)alloc(sizeof(double));
  unsigned long long* pos_cnt = (unsigned long long*)alloc(sizeof(unsigned long long));
  size_t zero_bytes = (size_t)(p - (char*)d_ws);
  // --- non-zeroed scratch ---
  float* dinv = (float*)alloc(sizeof(float) * N);
  int* off = (int*)alloc(sizeof(int) * (N + 1));
  int* csr = (int*)alloc(sizeof(int) * E);
  float* bufA = (float*)alloc(sizeof(float) * (size_t)N * HDIM);  // xW1, then h@W2
  float* bufB = (float*)alloc(sizeof(float) * (size_t)N * HDIM);  // h (post-relu)
  float* bufC = (float*)alloc(sizeof(float) * (size_t)N * HDIM);  // z

  hipMemsetAsync(d_ws, 0, zero_bytes, stream);

  const int tb = 256;
  count_kernel<<<(E + tb - 1) / tb, tb, 0, stream>>>(dst, cnt, E);
  dinv_kernel<<<(N + tb - 1) / tb, tb, 0, stream>>>(cnt, dinv, N);
  scan_kernel<<<1, 1024, 0, stream>>>(cnt, off, N);
  fill_kernel<<<(E + tb - 1) / tb, tb, 0, stream>>>(src, dst, off, fill, csr, E);

  gemm_kernel<FIN><<<(N + 3) / 4, tb, 0, stream>>>(x, W1, bufA, N);
  conv_relu_kernel<<<(N + 3) / 4, tb, 0, stream>>>(bufA, csr, off, dinv, b1, bufB, N);
  gemm_kernel<HDIM><<<(N + 3) / 4, tb, 0, stream>>>(bufB, W2, bufA, N);
  conv_norm_kernel<<<(N + 3) / 4, tb, 0, stream>>>(bufA, csr, off, dinv, b2, bufC, sumz, N);

  // 1500 blocks * 4 waves = 6000 waves * 64 = exactly E edges per sweep
  pos_kernel<<<1500, tb, 0, stream>>>(src, dst, bufC, hash, pos_sum, pos_cnt, E, N);
  finalize_kernel<<<1, 64, 0, stream>>>(sumz, pos_sum, pos_cnt, out, N);
}

// Round 3
// 306.637 us; speedup vs baseline: 1.2262x; 1.2262x over previous
//
#include <hip/hip_runtime.h>

// CommunityGNN: 2× GCNConv + contrastive loss, N=12000, E=384000, F_IN=128, H=64.
// Key algebra: sim.sum() == ||sum_i z_i||^2  (never materialize N×N sim);
// pos_sum = sum over UNIQUE edges of z[s]·z[d]  (pos_mask .at[].set() dedupes).
// Layout: ELL adjacency (width 96 >> max degree ~57 of Poisson(32)), no scan.

constexpr int HDIM = 64;
constexpr int FIN = 128;
constexpr int ELLW = 96;
constexpr unsigned HASH_BITS = 20;
constexpr unsigned HASH_SIZE = 1u << HASH_BITS;   // 1M slots, load factor ~0.37
constexpr unsigned HASH_MASK = HASH_SIZE - 1u;

// Fused degree-count + ELL scatter: slot = old count.
__global__ void fill_kernel(const int* __restrict__ src, const int* __restrict__ dst,
                            int* __restrict__ cnt, int* __restrict__ ell, int E) {
  int e = blockIdx.x * blockDim.x + threadIdx.x;
  if (e < E) {
    int d = dst[e];
    int slot = atomicAdd(&cnt[d], 1);
    if (slot < ELLW) ell[(size_t)d * ELLW + slot] = src[e];
  }
}

__global__ void dinv_kernel(const int* __restrict__ cnt, float* __restrict__ dinv, int n) {
  int v = blockIdx.x * blockDim.x + threadIdx.x;
  if (v < n) dinv[v] = rsqrtf((float)(cnt[v] + 1));  // +1 = self loop
}

// out[n,64] = A[n,K] @ W[K,64]. Block = 256 threads = 4 rows × 64 cols; W in LDS.
// Dual accumulators break the K-deep FMA dependency chain.
template <int K>
__global__ void gemm_kernel(const float* __restrict__ A, const float* __restrict__ W,
                            float* __restrict__ out, int n) {
  __shared__ float w[K * HDIM];
  for (int i = threadIdx.x; i < K * HDIM; i += 256) w[i] = W[i];
  __syncthreads();
  int col = threadIdx.x & 63;
  int row = blockIdx.x * 4 + (threadIdx.x >> 6);
  if (row >= n) return;
  const float* a = A + (size_t)row * K;
  float acc0 = 0.f, acc1 = 0.f;
#pragma unroll
  for (int k = 0; k < K; k += 2) {
    acc0 = fmaf(a[k], w[k * HDIM + col], acc0);
    acc1 = fmaf(a[k + 1], w[(k + 1) * HDIM + col], acc1);
  }
  out[(size_t)row * HDIM + col] = acc0 + acc1;
}

// GCN aggregation over ELL rows. One wave per node, lane = feature.
// Lanes prefetch up to 64 neighbor (idx, dinv) pairs in parallel, then an
// unrolled sweep of shfl-broadcast neighbors keeps 4 row-loads in flight.
// RELU: h = relu(agg + b). NORM: z = normalize(agg + b) + fused column-sum.
template <bool NORM>
__global__ void conv_kernel(const float* __restrict__ hin, const int* __restrict__ ell,
                            const int* __restrict__ cnt, const float* __restrict__ dinv,
                            const float* __restrict__ bias, float* __restrict__ out,
                            double* __restrict__ sumz, int n) {
  __shared__ double lds[4][HDIM];
  const int wv = threadIdx.x >> 6, lane = threadIdx.x & 63;
  const int v = blockIdx.x * 4 + wv;
  double zv = 0.0;
  if (v < n) {
    const float dv = dinv[v];
    float acc0 = hin[(size_t)v * HDIM + lane] * (dv * dv);  // self loop
    float acc1 = 0.f;
    const int deg = cnt[v];
    const int* __restrict__ row = ell + (size_t)v * ELLW;
    for (int base = 0; base < deg; base += 64) {
      const int mm = min(deg - base, 64);
      int idx = (lane < mm) ? row[base + lane] : 0;
      float wt = ((lane < mm) ? dinv[idx] : 0.f) * dv;
      int b = 0;
      for (; b + 4 <= mm; b += 4) {
        int s0 = __shfl(idx, b, 64), s1 = __shfl(idx, b + 1, 64);
        int s2 = __shfl(idx, b + 2, 64), s3 = __shfl(idx, b + 3, 64);
        float w0 = __shfl(wt, b, 64), w1 = __shfl(wt, b + 1, 64);
        float w2 = __shfl(wt, b + 2, 64), w3 = __shfl(wt, b + 3, 64);
        float r0 = hin[(size_t)s0 * HDIM + lane];
        float r1 = hin[(size_t)s1 * HDIM + lane];
        float r2 = hin[(size_t)s2 * HDIM + lane];
        float r3 = hin[(size_t)s3 * HDIM + lane];
        acc0 = fmaf(r0, w0, acc0);
        acc1 = fmaf(r1, w1, acc1);
        acc0 = fmaf(r2, w2, acc0);
        acc1 = fmaf(r3, w3, acc1);
      }
      for (; b < mm; ++b) {
        int s0 = __shfl(idx, b, 64);
        float w0 = __shfl(wt, b, 64);
        acc0 = fmaf(hin[(size_t)s0 * HDIM + lane], w0, acc0);
      }
    }
    float acc = acc0 + acc1 + bias[lane];
    if (!NORM) {
      out[(size_t)v * HDIM + lane] = fmaxf(acc, 0.f);
    } else {
      float ss = acc * acc;
#pragma unroll
      for (int o = 32; o; o >>= 1) ss += __shfl_xor(ss, o, 64);
      float zf = acc / fmaxf(sqrtf(ss), 1e-12f);
      out[(size_t)v * HDIM + lane] = zf;
      zv = (double)zf;
    }
  }
  if (NORM) {
    lds[wv][lane] = zv;
    __syncthreads();
    if (wv == 0) {
      double t = lds[0][lane] + lds[1][lane] + lds[2][lane] + lds[3][lane];
      atomicAdd(&sumz[lane], t);
    }
  }
}

// Unique-edge dot products. Each wave owns a batch of 64 edges: all 64 lanes
// hash-probe in parallel, then a STATIC 64-iteration sweep (pipelineable
// independent loads) accumulates the unique edges' per-lane products.
__global__ void pos_kernel(const int* __restrict__ src, const int* __restrict__ dst,
                           const float* __restrict__ z, unsigned* __restrict__ hash,
                           double* __restrict__ pos_sum, unsigned long long* __restrict__ pos_cnt,
                           int E, int n) {
  const int lane = threadIdx.x & 63;
  const int wid = (blockIdx.x * blockDim.x + threadIdx.x) >> 6;
  const int nw = (gridDim.x * blockDim.x) >> 6;
  double acc = 0.0;
  unsigned long long lcnt = 0;
  for (int base = wid * 64; base < E; base += nw * 64) {
    const int e = base + lane;
    int s = 0, d = 0, isnew = 0;
    if (e < E) {
      s = src[e];
      d = dst[e];
      unsigned key = (unsigned)s * (unsigned)n + (unsigned)d + 1u;  // nonzero, < 2^31
      unsigned hsh = (key * 2654435761u) & HASH_MASK;
      for (;;) {
        unsigned prev = atomicCAS(&hash[hsh], 0u, key);
        if (prev == 0u) { isnew = 1; break; }
        if (prev == key) break;
        hsh = (hsh + 1u) & HASH_MASK;
      }
    }
    const unsigned long long mask = __ballot(isnew != 0);
    if (lane == 0) lcnt += (unsigned long long)__popcll(mask);
    float facc = 0.f;
#pragma unroll 8
    for (int b = 0; b < 64; ++b) {
      int ss = __shfl(s, b, 64);
      int dd = __shfl(d, b, 64);
      float p = z[(size_t)ss * HDIM + lane] * z[(size_t)dd * HDIM + lane];
      facc += ((mask >> b) & 1ull) ? p : 0.f;
    }
    acc += (double)facc;
  }
#pragma unroll
  for (int o = 32; o; o >>= 1) acc += __shfl_xor(acc, o, 64);
  if (lane == 0) {
    if (acc != 0.0) atomicAdd(pos_sum, acc);
    if (lcnt) atomicAdd(pos_cnt, lcnt);
  }
}

__global__ void finalize_kernel(const double* __restrict__ sumz, const double* __restrict__ pos_sum,
                                const unsigned long long* __restrict__ pos_cnt,
                                float* __restrict__ out, int n) {
  if (threadIdx.x == 0 && blockIdx.x == 0) {
    double tot = 0.0;
    for (int k = 0; k < HDIM; ++k) { double s = sumz[k]; tot += s * s; }
    double ps = *pos_sum;
    double pc = (double)*pos_cnt;
    double n2 = (double)n * (double)n;
    out[0] = (float)(-(ps / pc) + (tot - ps) / (n2 - pc));
  }
}

extern "C" void kernel_launch(void* const* d_in, const int* in_sizes, int n_in,
                              void* d_out, int out_size, void* d_ws, size_t ws_size,
                              hipStream_t stream) {
  (void)n_in; (void)out_size; (void)ws_size;
  const float* x  = (const float*)d_in[0];
  const int* eidx = (const int*)d_in[1];
  const float* W1 = (const float*)d_in[2];
  const float* b1 = (const float*)d_in[3];
  const float* W2 = (const float*)d_in[4];
  const float* b2 = (const float*)d_in[5];
  float* out = (float*)d_out;

  const int N = in_sizes[0] / FIN;   // 12000
  const int E = in_sizes[1] / 2;     // 384000
  const int* src = eidx;
  const int* dst = eidx + E;

  char* p = (char*)d_ws;
  auto alloc = [&](size_t bytes) -> void* {
    void* r = (void*)p;
    p += (bytes + 255) & ~(size_t)255;
    return r;
  };
  // --- zeroed region (one contiguous memset) ---
  unsigned* hash = (unsigned*)alloc(sizeof(unsigned) * HASH_SIZE);  // 4 MB
  int* cnt = (int*)alloc(sizeof(int) * N);
  double* sumz = (double*)alloc(sizeof(double) * HDIM);
  double* pos_sum = (double*)alloc(sizeof(double));
  unsigned long long* pos_cnt = (unsigned long long*)alloc(sizeof(unsigned long long));
  size_t zero_bytes = (size_t)(p - (char*)d_ws);
  // --- non-zeroed scratch ---
  float* dinv = (float*)alloc(sizeof(float) * N);
  int* ell = (int*)alloc(sizeof(int) * (size_t)N * ELLW);           // 4.6 MB
  float* bufA = (float*)alloc(sizeof(float) * (size_t)N * HDIM);   // xW1, then h@W2
  float* bufB = (float*)alloc(sizeof(float) * (size_t)N * HDIM);   // h (post-relu)
  float* bufC = (float*)alloc(sizeof(float) * (size_t)N * HDIM);   // z

  hipMemsetAsync(d_ws, 0, zero_bytes, stream);

  const int tb = 256;
  fill_kernel<<<(E + tb - 1) / tb, tb, 0, stream>>>(src, dst, cnt, ell, E);
  dinv_kernel<<<(N + tb - 1) / tb, tb, 0, stream>>>(cnt, dinv, N);

  gemm_kernel<FIN><<<(N + 3) / 4, tb, 0, stream>>>(x, W1, bufA, N);
  conv_kernel<false><<<(N + 3) / 4, tb, 0, stream>>>(bufA, ell, cnt, dinv, b1, bufB, nullptr, N);
  gemm_kernel<HDIM><<<(N + 3) / 4, tb, 0, stream>>>(bufB, W2, bufA, N);
  conv_kernel<true><<<(N + 3) / 4, tb, 0, stream>>>(bufA, ell, cnt, dinv, b2, bufC, sumz, N);

  // 1500 blocks * 4 waves * 64 lanes = exactly E edges per sweep
  pos_kernel<<<1500, tb, 0, stream>>>(src, dst, bufC, hash, pos_sum, pos_cnt, E, N);
  finalize_kernel<<<1, 64, 0, stream>>>(sumz, pos_sum, pos_cnt, out, N);
}

// Round 7
// 303.945 us; speedup vs baseline: 1.2371x; 1.0089x over previous
//
#include <hip/hip_runtime.h>

// CommunityGNN: 2× GCNConv + contrastive loss, N=12000, E=384000, F_IN=128, H=64.
// Key algebra: sim.sum() == ||sum_i z_i||^2  (never materialize N×N sim);
// pos_sum = sum over UNIQUE edges of z[s]·z[d]  (pos_mask .at[].set() dedupes).
// Dedup strategy: partition edges into 1024 buckets by key-hash (duplicates
// collide into the same bucket), then block-local LDS-hash dedup — NO scattered
// global atomics (round-3 counters showed 384k global atomicCAS = 49 MB of
// HBM RMW traffic = the whole 97 µs).

constexpr int HDIM = 64;
constexpr int FIN = 128;
constexpr int ELLW = 96;      // >> max degree ~57 of Poisson(32)
constexpr int NB = 1024;      // edge buckets
constexpr int BCAP = 512;     // mean 375, +7 sigma safe
constexpr int LHASH = 2048;   // per-block LDS hash slots

// Fused: degree count + ELL scatter + edge bucketing.
__global__ void fill_kernel(const int* __restrict__ src, const int* __restrict__ dst,
                            int* __restrict__ cnt, int* __restrict__ ell,
                            int* __restrict__ bcnt, unsigned long long* __restrict__ bucket,
                            int E, int n) {
  int e = blockIdx.x * blockDim.x + threadIdx.x;
  if (e >= E) return;
  int s = src[e], d = dst[e];
  int slot = atomicAdd(&cnt[d], 1);
  if (slot < ELLW) ell[(size_t)d * ELLW + slot] = s;
  unsigned key = (unsigned)s * (unsigned)n + (unsigned)d;
  unsigned b = (key * 2654435761u) >> 22;  // top 10 bits -> 1024 buckets
  int bs = atomicAdd(&bcnt[b], 1);
  if (bs < BCAP) bucket[(size_t)b * BCAP + bs] = ((unsigned long long)(unsigned)s << 32) | (unsigned)d;
}

__global__ void dinv_kernel(const int* __restrict__ cnt, float* __restrict__ dinv, int n) {
  int v = blockIdx.x * blockDim.x + threadIdx.x;
  if (v < n) dinv[v] = rsqrtf((float)(cnt[v] + 1));  // +1 = self loop
}

// out[n,64] = A[n,K] @ W[K,64]. Block = 256 threads = 4 rows × 64 cols; W in LDS.
template <int K>
__global__ void gemm_kernel(const float* __restrict__ A, const float* __restrict__ W,
                            float* __restrict__ out, int n) {
  __shared__ float w[K * HDIM];
  for (int i = threadIdx.x; i < K * HDIM; i += 256) w[i] = W[i];
  __syncthreads();
  int col = threadIdx.x & 63;
  int row = blockIdx.x * 4 + (threadIdx.x >> 6);
  if (row >= n) return;
  const float* a = A + (size_t)row * K;
  float acc0 = 0.f, acc1 = 0.f;
#pragma unroll
  for (int k = 0; k < K; k += 2) {
    acc0 = fmaf(a[k], w[k * HDIM + col], acc0);
    acc1 = fmaf(a[k + 1], w[(k + 1) * HDIM + col], acc1);
  }
  out[(size_t)row * HDIM + col] = acc0 + acc1;
}

// GCN aggregation over ELL rows. One wave per node, lane = feature.
template <bool NORM>
__global__ void conv_kernel(const float* __restrict__ hin, const int* __restrict__ ell,
                            const int* __restrict__ cnt, const float* __restrict__ dinv,
                            const float* __restrict__ bias, float* __restrict__ out,
                            double* __restrict__ sumz, int n) {
  __shared__ double lds[4][HDIM];
  const int wv = threadIdx.x >> 6, lane = threadIdx.x & 63;
  const int v = blockIdx.x * 4 + wv;
  double zv = 0.0;
  if (v < n) {
    const float dv = dinv[v];
    float acc0 = hin[(size_t)v * HDIM + lane] * (dv * dv);  // self loop
    float acc1 = 0.f;
    const int deg = cnt[v];
    const int* __restrict__ row = ell + (size_t)v * ELLW;
    for (int base = 0; base < deg; base += 64) {
      const int mm = min(deg - base, 64);
      int idx = (lane < mm) ? row[base + lane] : 0;
      float wt = ((lane < mm) ? dinv[idx] : 0.f) * dv;
      int b = 0;
      for (; b + 4 <= mm; b += 4) {
        int s0 = __shfl(idx, b, 64), s1 = __shfl(idx, b + 1, 64);
        int s2 = __shfl(idx, b + 2, 64), s3 = __shfl(idx, b + 3, 64);
        float w0 = __shfl(wt, b, 64), w1 = __shfl(wt, b + 1, 64);
        float w2 = __shfl(wt, b + 2, 64), w3 = __shfl(wt, b + 3, 64);
        float r0 = hin[(size_t)s0 * HDIM + lane];
        float r1 = hin[(size_t)s1 * HDIM + lane];
        float r2 = hin[(size_t)s2 * HDIM + lane];
        float r3 = hin[(size_t)s3 * HDIM + lane];
        acc0 = fmaf(r0, w0, acc0);
        acc1 = fmaf(r1, w1, acc1);
        acc0 = fmaf(r2, w2, acc0);
        acc1 = fmaf(r3, w3, acc1);
      }
      for (; b < mm; ++b) {
        int s0 = __shfl(idx, b, 64);
        float w0 = __shfl(wt, b, 64);
        acc0 = fmaf(hin[(size_t)s0 * HDIM + lane], w0, acc0);
      }
    }
    float acc = acc0 + acc1 + bias[lane];
    if (!NORM) {
      out[(size_t)v * HDIM + lane] = fmaxf(acc, 0.f);
    } else {
      float ss = acc * acc;
#pragma unroll
      for (int o = 32; o; o >>= 1) ss += __shfl_xor(ss, o, 64);
      float zf = acc / fmaxf(sqrtf(ss), 1e-12f);
      out[(size_t)v * HDIM + lane] = zf;
      zv = (double)zf;
    }
  }
  if (NORM) {
    lds[wv][lane] = zv;
    __syncthreads();
    if (wv == 0) {
      double t = lds[0][lane] + lds[1][lane] + lds[2][lane] + lds[3][lane];
      atomicAdd(&sumz[lane], t);
    }
  }
}

// One block per bucket. LDS-hash dedup (cheap), then dot products with
// 2 edges per wave-instruction (32 lanes × float2 per row).
__global__ __launch_bounds__(256) void pos_kernel(
    const unsigned long long* __restrict__ bucket, const int* __restrict__ bcnt,
    const float* __restrict__ z, double* __restrict__ pos_partial,
    int* __restrict__ cnt_partial, int n) {
  __shared__ unsigned lhash[LHASH];
  __shared__ double redp[4];
  __shared__ int redc[4];
  const int tid = threadIdx.x, lane = tid & 63, wv = tid >> 6;
  const int b = blockIdx.x;
  for (int i = tid; i < LHASH; i += 256) lhash[i] = 0u;
  __syncthreads();
  const int cb = min(bcnt[b], BCAP);
  const unsigned long long* __restrict__ be = bucket + (size_t)b * BCAP;
  const float2* __restrict__ z2 = (const float2*)z;
  const int h5 = lane >> 5;          // which edge of the pair this lane serves
  const int fb = lane & 31;          // float2 index within the row
  double acc = 0.0;
  int ucnt = 0;
  for (int base = wv * 64; base < cb; base += 256) {
    const int e = base + lane;
    int s = 0, d = 0, isnew = 0;
    if (e < cb) {
      unsigned long long pk = be[e];
      s = (int)(pk >> 32);
      d = (int)(pk & 0xffffffffu);
      unsigned key = (unsigned)s * (unsigned)n + (unsigned)d + 1u;  // nonzero
      unsigned h = (key * 0x9E3779B1u) & (LHASH - 1);
      for (;;) {
        unsigned prev = atomicCAS(&lhash[h], 0u, key);
        if (prev == 0u) { isnew = 1; break; }
        if (prev == key) break;
        h = (h + 1) & (LHASH - 1);
      }
    }
    const unsigned long long mask = __ballot(isnew != 0);
    ucnt += __popcll(mask);
    if (!mask) continue;
    float facc = 0.f;
#pragma unroll 8
    for (int q = 0; q < 32; ++q) {
      int sl = 2 * q + h5;  // lanes 0-31: edge 2q, lanes 32-63: edge 2q+1
      int ss = __shfl(s, sl, 64);
      int dd = __shfl(d, sl, 64);
      float2 a = z2[(size_t)ss * 32 + fb];
      float2 c = z2[(size_t)dd * 32 + fb];
      float p = a.x * c.x + a.y * c.y;
      facc += ((mask >> sl) & 1ull) ? p : 0.f;
    }
    acc += (double)facc;
  }
#pragma unroll
  for (int o = 32; o; o >>= 1) acc += __shfl_xor(acc, o, 64);
  if (lane == 0) { redp[wv] = acc; redc[wv] = ucnt; }
  __syncthreads();
  if (tid == 0) {
    pos_partial[b] = redp[0] + redp[1] + redp[2] + redp[3];
    cnt_partial[b] = redc[0] + redc[1] + redc[2] + redc[3];
  }
}

__global__ void finalize_kernel(const double* __restrict__ sumz,
                                const double* __restrict__ pos_partial,
                                const int* __restrict__ cnt_partial,
                                float* __restrict__ out, int n) {
  const int tid = threadIdx.x, lane = tid & 63, wv = tid >> 6;
  double ps = 0.0;
  long long pc = 0;
  for (int i = tid; i < NB; i += 256) { ps += pos_partial[i]; pc += (long long)cnt_partial[i]; }
#pragma unroll
  for (int o = 32; o; o >>= 1) { ps += __shfl_xor(ps, o, 64); pc += __shfl_xor(pc, o, 64); }
  __shared__ double lps[4];
  __shared__ long long lpc[4];
  if (lane == 0) { lps[wv] = ps; lpc[wv] = pc; }
  __syncthreads();
  if (tid == 0) {
    double P = lps[0] + lps[1] + lps[2] + lps[3];
    double C = (double)(lpc[0] + lpc[1] + lpc[2] + lpc[3]);
    double tot = 0.0;
    for (int k = 0; k < HDIM; ++k) { double s = sumz[k]; tot += s * s; }
    double n2 = (double)n * (double)n;
    out[0] = (float)(-(P / C) + (tot - P) / (n2 - C));
  }
}

extern "C" void kernel_launch(void* const* d_in, const int* in_sizes, int n_in,
                              void* d_out, int out_size, void* d_ws, size_t ws_size,
                              hipStream_t stream) {
  (void)n_in; (void)out_size; (void)ws_size;
  const float* x  = (const float*)d_in[0];
  const int* eidx = (const int*)d_in[1];
  const float* W1 = (const float*)d_in[2];
  const float* b1 = (const float*)d_in[3];
  const float* W2 = (const float*)d_in[4];
  const float* b2 = (const float*)d_in[5];
  float* out = (float*)d_out;

  const int N = in_sizes[0] / FIN;   // 12000
  const int E = in_sizes[1] / 2;     // 384000
  const int* src = eidx;
  const int* dst = eidx + E;

  char* p = (char*)d_ws;
  auto alloc = [&](size_t bytes) -> void* {
    void* r = (void*)p;
    p += (bytes + 255) & ~(size_t)255;
    return r;
  };
  // --- zeroed region (one contiguous, now tiny: ~70 KB) ---
  int* cnt = (int*)alloc(sizeof(int) * N);
  int* bcnt = (int*)alloc(sizeof(int) * NB);
  double* sumz = (double*)alloc(sizeof(double) * HDIM);
  size_t zero_bytes = (size_t)(p - (char*)d_ws);
  // --- non-zeroed scratch ---
  double* pos_partial = (double*)alloc(sizeof(double) * NB);
  int* cnt_partial = (int*)alloc(sizeof(int) * NB);
  float* dinv = (float*)alloc(sizeof(float) * N);
  int* ell = (int*)alloc(sizeof(int) * (size_t)N * ELLW);                      // 4.6 MB
  unsigned long long* bucket = (unsigned long long*)alloc(sizeof(unsigned long long) * (size_t)NB * BCAP);  // 4 MB
  float* bufA = (float*)alloc(sizeof(float) * (size_t)N * HDIM);  // xW1, then h@W2
  float* bufB = (float*)alloc(sizeof(float) * (size_t)N * HDIM);  // h (post-relu)
  float* bufC = (float*)alloc(sizeof(float) * (size_t)N * HDIM);  // z

  hipMemsetAsync(d_ws, 0, zero_bytes, stream);

  const int tb = 256;
  fill_kernel<<<(E + tb - 1) / tb, tb, 0, stream>>>(src, dst, cnt, ell, bcnt, bucket, E, N);
  dinv_kernel<<<(N + tb - 1) / tb, tb, 0, stream>>>(cnt, dinv, N);

  gemm_kernel<FIN><<<(N + 3) / 4, tb, 0, stream>>>(x, W1, bufA, N);
  conv_kernel<false><<<(N + 3) / 4, tb, 0, stream>>>(bufA, ell, cnt, dinv, b1, bufB, nullptr, N);
  gemm_kernel<HDIM><<<(N + 3) / 4, tb, 0, stream>>>(bufB, W2, bufA, N);
  conv_kernel<true><<<(N + 3) / 4, tb, 0, stream>>>(bufA, ell, cnt, dinv, b2, bufC, sumz, N);

  pos_kernel<<<NB, tb, 0, stream>>>(bucket, bcnt, bufC, pos_partial, cnt_partial, N);
  finalize_kernel<<<1, tb, 0, stream>>>(sumz, pos_partial, cnt_partial, out, N);
}

// Round 10
// 254.036 us; speedup vs baseline: 1.4802x; 1.1965x over previous
//
#include <hip/hip_runtime.h>

// CommunityGNN: 2× GCNConv + contrastive loss, N=12000, E=384000, F_IN=128, H=64.
// Key algebra: sim.sum() == ||sum_i z_i||^2  (never materialize N×N sim);
// pos_sum = sum over UNIQUE edges of z[s]·z[d]  (pos_mask .at[].set() dedupes).
// R7 counters: fill_kernel 97µs, WRITE_SIZE 41.7MB = scattered-line RMW bound.
// Fix: (a) drop the bucket array — ELL rows already group duplicate (s,d) by
// row d, so dedup runs per-row in pos_kernel (all-pairs shfl, 2-batch);
// (b) ELL as ushort (N<65536): mean row = 64B = 1 dirty line, ~4× less
// scattered-write traffic overall.

constexpr int HDIM = 64;
constexpr int FIN = 128;
constexpr int ELLW = 96;      // max in-degree of Binom(384k, 1/12k) ~ 63; 96 = safe

// Fused degree-count + ushort-ELL scatter. Only scattered structure left.
__global__ void fill_kernel(const int* __restrict__ src, const int* __restrict__ dst,
                            int* __restrict__ cnt, ushort* __restrict__ ell, int E) {
  int e = blockIdx.x * blockDim.x + threadIdx.x;
  if (e >= E) return;
  int s = src[e], d = dst[e];
  int slot = atomicAdd(&cnt[d], 1);
  if (slot < ELLW) ell[(size_t)d * ELLW + slot] = (ushort)s;
}

__global__ void dinv_kernel(const int* __restrict__ cnt, float* __restrict__ dinv, int n) {
  int v = blockIdx.x * blockDim.x + threadIdx.x;
  if (v < n) dinv[v] = rsqrtf((float)(cnt[v] + 1));  // +1 = self loop
}

// out[n,64] = A[n,K] @ W[K,64]. Block = 256 threads = 4 rows × 64 cols; W in LDS.
template <int K>
__global__ void gemm_kernel(const float* __restrict__ A, const float* __restrict__ W,
                            float* __restrict__ out, int n) {
  __shared__ float w[K * HDIM];
  for (int i = threadIdx.x; i < K * HDIM; i += 256) w[i] = W[i];
  __syncthreads();
  int col = threadIdx.x & 63;
  int row = blockIdx.x * 4 + (threadIdx.x >> 6);
  if (row >= n) return;
  const float* a = A + (size_t)row * K;
  float acc0 = 0.f, acc1 = 0.f;
#pragma unroll
  for (int k = 0; k < K; k += 2) {
    acc0 = fmaf(a[k], w[k * HDIM + col], acc0);
    acc1 = fmaf(a[k + 1], w[(k + 1) * HDIM + col], acc1);
  }
  out[(size_t)row * HDIM + col] = acc0 + acc1;
}

// GCN aggregation over ushort-ELL rows. One wave per node, lane = feature.
template <bool NORM>
__global__ void conv_kernel(const float* __restrict__ hin, const ushort* __restrict__ ell,
                            const int* __restrict__ cnt, const float* __restrict__ dinv,
                            const float* __restrict__ bias, float* __restrict__ out,
                            double* __restrict__ sumz, int n) {
  __shared__ double lds[4][HDIM];
  const int wv = threadIdx.x >> 6, lane = threadIdx.x & 63;
  const int v = blockIdx.x * 4 + wv;
  double zv = 0.0;
  if (v < n) {
    const float dv = dinv[v];
    float acc0 = hin[(size_t)v * HDIM + lane] * (dv * dv);  // self loop
    float acc1 = 0.f;
    const int deg = min(cnt[v], ELLW);
    const ushort* __restrict__ row = ell + (size_t)v * ELLW;
    for (int base = 0; base < deg; base += 64) {
      const int mm = min(deg - base, 64);
      int idx = (lane < mm) ? (int)row[base + lane] : 0;
      float wt = ((lane < mm) ? dinv[idx] : 0.f) * dv;
      int b = 0;
      for (; b + 4 <= mm; b += 4) {
        int s0 = __shfl(idx, b, 64), s1 = __shfl(idx, b + 1, 64);
        int s2 = __shfl(idx, b + 2, 64), s3 = __shfl(idx, b + 3, 64);
        float w0 = __shfl(wt, b, 64), w1 = __shfl(wt, b + 1, 64);
        float w2 = __shfl(wt, b + 2, 64), w3 = __shfl(wt, b + 3, 64);
        float r0 = hin[(size_t)s0 * HDIM + lane];
        float r1 = hin[(size_t)s1 * HDIM + lane];
        float r2 = hin[(size_t)s2 * HDIM + lane];
        float r3 = hin[(size_t)s3 * HDIM + lane];
        acc0 = fmaf(r0, w0, acc0);
        acc1 = fmaf(r1, w1, acc1);
        acc0 = fmaf(r2, w2, acc0);
        acc1 = fmaf(r3, w3, acc1);
      }
      for (; b < mm; ++b) {
        int s0 = __shfl(idx, b, 64);
        float w0 = __shfl(wt, b, 64);
        acc0 = fmaf(hin[(size_t)s0 * HDIM + lane], w0, acc0);
      }
    }
    float acc = acc0 + acc1 + bias[lane];
    if (!NORM) {
      out[(size_t)v * HDIM + lane] = fmaxf(acc, 0.f);
    } else {
      float ss = acc * acc;
#pragma unroll
      for (int o = 32; o; o >>= 1) ss += __shfl_xor(ss, o, 64);
      float zf = acc / fmaxf(sqrtf(ss), 1e-12f);
      out[(size_t)v * HDIM + lane] = zf;
      zv = (double)zf;
    }
  }
  if (NORM) {
    lds[wv][lane] = zv;
    __syncthreads();
    if (wv == 0) {
      double t = lds[0][lane] + lds[1][lane] + lds[2][lane] + lds[3][lane];
      atomicAdd(&sumz[lane], t);
    }
  }
}

// Unique-edge dot products straight off the ELL: duplicates of (s,d) are in
// the same row d, so per-row all-pairs dedup (shfl) suffices. One wave per
// node; dot sweep = 2 edges per iteration via float2 half-waves.
__global__ __launch_bounds__(256) void pos_kernel(
    const ushort* __restrict__ ell, const int* __restrict__ cnt,
    const float* __restrict__ z, double* __restrict__ pos_sum,
    unsigned long long* __restrict__ pos_cnt, int n) {
  __shared__ double redp[4];
  __shared__ int redc[4];
  const int wv = threadIdx.x >> 6, lane = threadIdx.x & 63;
  const int v = blockIdx.x * 4 + wv;
  double acc = 0.0;
  int ucnt = 0;
  if (v < n) {
    const int deg = min(cnt[v], ELLW);
    const ushort* __restrict__ row = ell + (size_t)v * ELLW;
    const int m0 = min(deg, 64);
    const int m1 = deg - m0;  // 0..32
    int s0 = (lane < m0) ? (int)row[lane] : -1;
    int s1 = (lane < m1) ? (int)row[64 + lane] : -1;
    // --- dedup: entry is duplicate iff an EARLIER entry has the same src ---
    int dup0 = 0, dup1 = 0;
#pragma unroll 8
    for (int j = 0; j < 64; ++j) {
      int vj = __shfl(s0, j, 64);
      if (j < lane && vj == s0) dup0 = 1;
      if (vj == s1) dup1 = 1;  // batch1 entries come after ALL batch0 entries
    }
    if (m1 > 0) {
#pragma unroll 8
      for (int j = 0; j < 64; ++j) {
        int vj = __shfl(s1, j, 64);
        if (j < lane && vj == s1) dup1 = 1;
      }
    }
    const unsigned long long u0 = __ballot(lane < m0 && !dup0);
    const unsigned long long u1 = (m1 > 0) ? __ballot(lane < m1 && !dup1) : 0ull;
    ucnt = __popcll(u0) + __popcll(u1);
    // --- dots: z[s]·z[v] for unique s; 2 edges per sweep (float2 half-waves) ---
    const float2* __restrict__ z2 = (const float2*)z;
    const int fb = lane & 31, h5 = lane >> 5;
    const float2 zvv = z2[(size_t)v * 32 + fb];
    float facc = 0.f;
    for (int q = 0; q < m0; q += 2) {
      int sl = q + h5;
      int ss = __shfl(s0, sl, 64);
      bool pred = (sl < m0) && ((u0 >> sl) & 1ull);
      float2 a = z2[(size_t)max(ss, 0) * 32 + fb];
      float p = a.x * zvv.x + a.y * zvv.y;
      facc += pred ? p : 0.f;
    }
    for (int q = 0; q < m1; q += 2) {
      int sl = q + h5;
      int ss = __shfl(s1, sl, 64);
      bool pred = (sl < m1) && ((u1 >> sl) & 1ull);
      float2 a = z2[(size_t)max(ss, 0) * 32 + fb];
      float p = a.x * zvv.x + a.y * zvv.y;
      facc += pred ? p : 0.f;
    }
    acc = (double)facc;
  }
#pragma unroll
  for (int o = 32; o; o >>= 1) acc += __shfl_xor(acc, o, 64);
  if (lane == 0) { redp[wv] = acc; redc[wv] = ucnt; }
  __syncthreads();
  if (threadIdx.x == 0) {
    double P = redp[0] + redp[1] + redp[2] + redp[3];
    int C = redc[0] + redc[1] + redc[2] + redc[3];
    if (P != 0.0) atomicAdd(pos_sum, P);
    if (C) atomicAdd(pos_cnt, (unsigned long long)C);
  }
}

__global__ void finalize_kernel(const double* __restrict__ sumz,
                                const double* __restrict__ pos_sum,
                                const unsigned long long* __restrict__ pos_cnt,
                                float* __restrict__ out, int n) {
  if (threadIdx.x == 0 && blockIdx.x == 0) {
    double tot = 0.0;
    for (int k = 0; k < HDIM; ++k) { double s = sumz[k]; tot += s * s; }
    double ps = *pos_sum;
    double pc = (double)*pos_cnt;
    double n2 = (double)n * (double)n;
    out[0] = (float)(-(ps / pc) + (tot - ps) / (n2 - pc));
  }
}

extern "C" void kernel_launch(void* const* d_in, const int* in_sizes, int n_in,
                              void* d_out, int out_size, void* d_ws, size_t ws_size,
                              hipStream_t stream) {
  (void)n_in; (void)out_size; (void)ws_size;
  const float* x  = (const float*)d_in[0];
  const int* eidx = (const int*)d_in[1];
  const float* W1 = (const float*)d_in[2];
  const float* b1 = (const float*)d_in[3];
  const float* W2 = (const float*)d_in[4];
  const float* b2 = (const float*)d_in[5];
  float* out = (float*)d_out;

  const int N = in_sizes[0] / FIN;   // 12000
  const int E = in_sizes[1] / 2;     // 384000
  const int* src = eidx;
  const int* dst = eidx + E;

  char* p = (char*)d_ws;
  auto alloc = [&](size_t bytes) -> void* {
    void* r = (void*)p;
    p += (bytes + 255) & ~(size_t)255;
    return r;
  };
  // --- zeroed region (one contiguous memset, ~50 KB) ---
  int* cnt = (int*)alloc(sizeof(int) * N);
  double* sumz = (double*)alloc(sizeof(double) * HDIM);
  double* pos_sum = (double*)alloc(sizeof(double));
  unsigned long long* pos_cnt = (unsigned long long*)alloc(sizeof(unsigned long long));
  size_t zero_bytes = (size_t)(p - (char*)d_ws);
  // --- non-zeroed scratch ---
  float* dinv = (float*)alloc(sizeof(float) * N);
  ushort* ell = (ushort*)alloc(sizeof(ushort) * (size_t)N * ELLW);  // 2.3 MB
  float* bufA = (float*)alloc(sizeof(float) * (size_t)N * HDIM);   // xW1, then h@W2
  float* bufB = (float*)alloc(sizeof(float) * (size_t)N * HDIM);   // h (post-relu)
  float* bufC = (float*)alloc(sizeof(float) * (size_t)N * HDIM);   // z

  hipMemsetAsync(d_ws, 0, zero_bytes, stream);

  const int tb = 256;
  fill_kernel<<<(E + tb - 1) / tb, tb, 0, stream>>>(src, dst, cnt, ell, E);
  dinv_kernel<<<(N + tb - 1) / tb, tb, 0, stream>>>(cnt, dinv, N);

  gemm_kernel<FIN><<<(N + 3) / 4, tb, 0, stream>>>(x, W1, bufA, N);
  conv_kernel<false><<<(N + 3) / 4, tb, 0, stream>>>(bufA, ell, cnt, dinv, b1, bufB, nullptr, N);
  gemm_kernel<HDIM><<<(N + 3) / 4, tb, 0, stream>>>(bufB, W2, bufA, N);
  conv_kernel<true><<<(N + 3) / 4, tb, 0, stream>>>(bufA, ell, cnt, dinv, b2, bufC, sumz, N);

  pos_kernel<<<(N + 3) / 4, tb, 0, stream>>>(ell, cnt, bufC, pos_sum, pos_cnt, N);
  finalize_kernel<<<1, 64, 0, stream>>>(sumz, pos_sum, pos_cnt, out, N);
}

// Round 11
// 251.203 us; speedup vs baseline: 1.4969x; 1.0113x over previous
//
#include <hip/hip_runtime.h>

// CommunityGNN: 2× GCNConv + contrastive loss, N=12000, E=384000, F_IN=128, H=64.
// sim.sum() == ||sum_i z_i||^2 ; pos_sum = unique-edge dots (per-ELL-row dedup).
// R10 counters: conv_kernel 2×73µs, VALUBusy 6%, HBM 3% = L2-latency-bound
// gather (1 row/instruction + per-neighbor ds_bpermute chain + 64-addr dinv
// gather on critical path). Fix: lane=(group g=lane>>4, quad f=lane&15):
// each instruction loads 4 rows × float4 = 1KB; dinv gathered once per row;
// 2 bpermute per 4 neighbors; unroll×2 => 2KB in flight per wave.

constexpr int HDIM = 64;
constexpr int FIN = 128;
constexpr int ELLW = 96;  // max in-degree of Binom(384k,1/12k) ~63; 96 safe

__global__ void fill_kernel(const int* __restrict__ src, const int* __restrict__ dst,
                            int* __restrict__ cnt, ushort* __restrict__ ell, int E) {
  int e = blockIdx.x * blockDim.x + threadIdx.x;
  if (e >= E) return;
  int s = src[e], d = dst[e];
  int slot = atomicAdd(&cnt[d], 1);
  if (slot < ELLW) ell[(size_t)d * ELLW + slot] = (ushort)s;
}

__global__ void dinv_kernel(const int* __restrict__ cnt, float* __restrict__ dinv, int n) {
  int v = blockIdx.x * blockDim.x + threadIdx.x;
  if (v < n) dinv[v] = rsqrtf((float)(cnt[v] + 1));  // +1 = self loop
}

// out[n,64] = A[n,K] @ W[K,64]. Block = 256 threads = 4 rows × 64 cols; W in LDS.
template <int K>
__global__ void gemm_kernel(const float* __restrict__ A, const float* __restrict__ W,
                            float* __restrict__ out, int n) {
  __shared__ float w[K * HDIM];
  for (int i = threadIdx.x; i < K * HDIM; i += 256) w[i] = W[i];
  __syncthreads();
  int col = threadIdx.x & 63;
  int row = blockIdx.x * 4 + (threadIdx.x >> 6);
  if (row >= n) return;
  const float* a = A + (size_t)row * K;
  float acc0 = 0.f, acc1 = 0.f;
#pragma unroll
  for (int k = 0; k < K; k += 2) {
    acc0 = fmaf(a[k], w[k * HDIM + col], acc0);
    acc1 = fmaf(a[k + 1], w[(k + 1) * HDIM + col], acc1);
  }
  out[(size_t)row * HDIM + col] = acc0 + acc1;
}

// GCN aggregation, float4-gather layout. One wave per node.
// lane = (g = lane>>4: neighbor slot within quad, f = lane&15: feature quad).
template <bool NORM>
__global__ __launch_bounds__(256) void conv_kernel(
    const float* __restrict__ hin, const ushort* __restrict__ ell,
    const int* __restrict__ cnt, const float* __restrict__ dinv,
    const float* __restrict__ bias, float* __restrict__ out,
    double* __restrict__ sumz, int n) {
  __shared__ double lds[4][HDIM];
  const int wv = threadIdx.x >> 6, lane = threadIdx.x & 63;
  const int g = lane >> 4, f = lane & 15;
  const int v = blockIdx.x * 4 + wv;
  const float4* __restrict__ hin4 = (const float4*)hin;
  if (v < n) {
    const int deg = min(cnt[v], ELLW);
    const float dv = dinv[v];
    const ushort* __restrict__ row = ell + (size_t)v * ELLW;
    const int m0 = min(deg, 64);
    // Per-lane prefetch: neighbor index + its dinv (one 64-addr gather, once).
    int us = (lane < m0) ? (int)row[lane] : 0;
    float wl = (lane < m0) ? dinv[us] : 0.f;
    float4 acc0 = {0.f, 0.f, 0.f, 0.f}, acc1 = {0.f, 0.f, 0.f, 0.f};
    int base = 0;
    for (; base + 8 <= m0; base += 8) {  // 8 neighbors per iter, 2KB in flight
      int j0 = base + g, j1 = base + 4 + g;
      int i0 = __shfl(us, j0, 64), i1 = __shfl(us, j1, 64);
      float w0 = __shfl(wl, j0, 64), w1 = __shfl(wl, j1, 64);
      float4 r0 = hin4[(size_t)i0 * 16 + f];
      float4 r1 = hin4[(size_t)i1 * 16 + f];
      acc0.x = fmaf(w0, r0.x, acc0.x); acc0.y = fmaf(w0, r0.y, acc0.y);
      acc0.z = fmaf(w0, r0.z, acc0.z); acc0.w = fmaf(w0, r0.w, acc0.w);
      acc1.x = fmaf(w1, r1.x, acc1.x); acc1.y = fmaf(w1, r1.y, acc1.y);
      acc1.z = fmaf(w1, r1.z, acc1.z); acc1.w = fmaf(w1, r1.w, acc1.w);
    }
    for (; base < m0; base += 4) {  // tail quads (zero-weight shfl srcs pad)
      int j = base + g;
      int i0 = __shfl(us, j, 64);
      float w0 = __shfl(wl, j, 64);
      float4 r0 = hin4[(size_t)i0 * 16 + f];
      acc0.x = fmaf(w0, r0.x, acc0.x); acc0.y = fmaf(w0, r0.y, acc0.y);
      acc0.z = fmaf(w0, r0.z, acc0.z); acc0.w = fmaf(w0, r0.w, acc0.w);
    }
    for (int b2 = 64; b2 < deg; b2 += 4) {  // ultra-rare deg>64 fallback
      int j = b2 + g;
      int idx = (j < deg) ? (int)row[j] : 0;
      float w0 = (j < deg) ? dinv[idx] : 0.f;
      float4 r0 = hin4[(size_t)idx * 16 + f];
      acc0.x = fmaf(w0, r0.x, acc0.x); acc0.y = fmaf(w0, r0.y, acc0.y);
      acc0.z = fmaf(w0, r0.z, acc0.z); acc0.w = fmaf(w0, r0.w, acc0.w);
    }
    acc0.x += acc1.x; acc0.y += acc1.y; acc0.z += acc1.z; acc0.w += acc1.w;
    // Reduce across the 4 neighbor groups (lanes with same f).
#pragma unroll
    for (int o = 16; o <= 32; o <<= 1) {
      acc0.x += __shfl_xor(acc0.x, o, 64);
      acc0.y += __shfl_xor(acc0.y, o, 64);
      acc0.z += __shfl_xor(acc0.z, o, 64);
      acc0.w += __shfl_xor(acc0.w, o, 64);
    }
    // t = dv*agg + dv^2*self + bias
    float4 hv = hin4[(size_t)v * 16 + f];
    float4 b4 = ((const float4*)bias)[f];
    float dv2 = dv * dv;
    float4 t;
    t.x = fmaf(dv, acc0.x, fmaf(dv2, hv.x, b4.x));
    t.y = fmaf(dv, acc0.y, fmaf(dv2, hv.y, b4.y));
    t.z = fmaf(dv, acc0.z, fmaf(dv2, hv.z, b4.z));
    t.w = fmaf(dv, acc0.w, fmaf(dv2, hv.w, b4.w));
    if (!NORM) {
      t.x = fmaxf(t.x, 0.f); t.y = fmaxf(t.y, 0.f);
      t.z = fmaxf(t.z, 0.f); t.w = fmaxf(t.w, 0.f);
      if (g == 0) ((float4*)out)[(size_t)v * 16 + f] = t;
    } else {
      float ss = t.x * t.x + t.y * t.y + t.z * t.z + t.w * t.w;
#pragma unroll
      for (int o = 1; o <= 8; o <<= 1) ss += __shfl_xor(ss, o, 64);  // over 16 f's
      float inv = 1.f / fmaxf(sqrtf(ss), 1e-12f);
      t.x *= inv; t.y *= inv; t.z *= inv; t.w *= inv;
      if (g == 0) {
        ((float4*)out)[(size_t)v * 16 + f] = t;
        lds[wv][4 * f + 0] = (double)t.x;
        lds[wv][4 * f + 1] = (double)t.y;
        lds[wv][4 * f + 2] = (double)t.z;
        lds[wv][4 * f + 3] = (double)t.w;
      }
    }
  } else if (NORM) {
    if (g == 0)
      for (int k = 0; k < 4; ++k) lds[wv][4 * f + k] = 0.0;
  }
  if (NORM) {
    __syncthreads();
    if (wv == 0) {
      double s = lds[0][lane] + lds[1][lane] + lds[2][lane] + lds[3][lane];
      atomicAdd(&sumz[lane], s);
    }
  }
}

// Unique-edge dot products off the ELL (duplicates share row d). One wave per
// node; all-pairs shfl dedup; float2 half-wave dot sweep (2 edges/iter).
__global__ __launch_bounds__(256) void pos_kernel(
    const ushort* __restrict__ ell, const int* __restrict__ cnt,
    const float* __restrict__ z, double* __restrict__ pos_sum,
    unsigned long long* __restrict__ pos_cnt, int n) {
  __shared__ double redp[4];
  __shared__ int redc[4];
  const int wv = threadIdx.x >> 6, lane = threadIdx.x & 63;
  const int v = blockIdx.x * 4 + wv;
  double acc = 0.0;
  int ucnt = 0;
  if (v < n) {
    const int deg = min(cnt[v], ELLW);
    const ushort* __restrict__ row = ell + (size_t)v * ELLW;
    const int m0 = min(deg, 64);
    const int m1 = deg - m0;  // 0..32
    int s0 = (lane < m0) ? (int)row[lane] : -1;
    int s1 = (lane < m1) ? (int)row[64 + lane] : -1;
    int dup0 = 0, dup1 = 0;
#pragma unroll 8
    for (int j = 0; j < 64; ++j) {
      int vj = __shfl(s0, j, 64);
      if (j < lane && vj == s0) dup0 = 1;
      if (vj == s1) dup1 = 1;  // batch1 comes after ALL batch0 entries
    }
    if (m1 > 0) {
#pragma unroll 8
      for (int j = 0; j < 64; ++j) {
        int vj = __shfl(s1, j, 64);
        if (j < lane && vj == s1) dup1 = 1;
      }
    }
    const unsigned long long u0 = __ballot(lane < m0 && !dup0);
    const unsigned long long u1 = (m1 > 0) ? __ballot(lane < m1 && !dup1) : 0ull;
    ucnt = __popcll(u0) + __popcll(u1);
    const float2* __restrict__ z2 = (const float2*)z;
    const int fb = lane & 31, h5 = lane >> 5;
    const float2 zvv = z2[(size_t)v * 32 + fb];
    float facc = 0.f;
    for (int q = 0; q < m0; q += 2) {
      int sl = q + h5;
      int ss = __shfl(s0, sl, 64);
      bool pred = (sl < m0) && ((u0 >> sl) & 1ull);
      float2 a = z2[(size_t)max(ss, 0) * 32 + fb];
      facc += pred ? (a.x * zvv.x + a.y * zvv.y) : 0.f;
    }
    for (int q = 0; q < m1; q += 2) {
      int sl = q + h5;
      int ss = __shfl(s1, sl, 64);
      bool pred = (sl < m1) && ((u1 >> sl) & 1ull);
      float2 a = z2[(size_t)max(ss, 0) * 32 + fb];
      facc += pred ? (a.x * zvv.x + a.y * zvv.y) : 0.f;
    }
    acc = (double)facc;
  }
#pragma unroll
  for (int o = 32; o; o >>= 1) acc += __shfl_xor(acc, o, 64);
  if (lane == 0) { redp[wv] = acc; redc[wv] = ucnt; }
  __syncthreads();
  if (threadIdx.x == 0) {
    double P = redp[0] + redp[1] + redp[2] + redp[3];
    int C = redc[0] + redc[1] + redc[2] + redc[3];
    if (P != 0.0) atomicAdd(pos_sum, P);
    if (C) atomicAdd(pos_cnt, (unsigned long long)C);
  }
}

__global__ void finalize_kernel(const double* __restrict__ sumz,
                                const double* __restrict__ pos_sum,
                                const unsigned long long* __restrict__ pos_cnt,
                                float* __restrict__ out, int n) {
  if (threadIdx.x == 0 && blockIdx.x == 0) {
    double tot = 0.0;
    for (int k = 0; k < HDIM; ++k) { double s = sumz[k]; tot += s * s; }
    double ps = *pos_sum;
    double pc = (double)*pos_cnt;
    double n2 = (double)n * (double)n;
    out[0] = (float)(-(ps / pc) + (tot - ps) / (n2 - pc));
  }
}

extern "C" void kernel_launch(void* const* d_in, const int* in_sizes, int n_in,
                              void* d_out, int out_size, void* d_ws, size_t ws_size,
                              hipStream_t stream) {
  (void)n_in; (void)out_size; (void)ws_size;
  const float* x  = (const float*)d_in[0];
  const int* eidx = (const int*)d_in[1];
  const float* W1 = (const float*)d_in[2];
  const float* b1 = (const float*)d_in[3];
  const float* W2 = (const float*)d_in[4];
  const float* b2 = (const float*)d_in[5];
  float* out = (float*)d_out;

  const int N = in_sizes[0] / FIN;   // 12000
  const int E = in_sizes[1] / 2;     // 384000
  const int* src = eidx;
  const int* dst = eidx + E;

  char* p = (char*)d_ws;
  auto alloc = [&](size_t bytes) -> void* {
    void* r = (void*)p;
    p += (bytes + 255) & ~(size_t)255;
    return r;
  };
  // --- zeroed region (one contiguous memset, ~50 KB) ---
  int* cnt = (int*)alloc(sizeof(int) * N);
  double* sumz = (double*)alloc(sizeof(double) * HDIM);
  double* pos_sum = (double*)alloc(sizeof(double));
  unsigned long long* pos_cnt = (unsigned long long*)alloc(sizeof(unsigned long long));
  size_t zero_bytes = (size_t)(p - (char*)d_ws);
  // --- non-zeroed scratch ---
  float* dinv = (float*)alloc(sizeof(float) * N);
  ushort* ell = (ushort*)alloc(sizeof(ushort) * (size_t)N * ELLW);  // 2.3 MB
  float* bufA = (float*)alloc(sizeof(float) * (size_t)N * HDIM);   // xW1, then h@W2
  float* bufB = (float*)alloc(sizeof(float) * (size_t)N * HDIM);   // h (post-relu)
  float* bufC = (float*)alloc(sizeof(float) * (size_t)N * HDIM);   // z

  hipMemsetAsync(d_ws, 0, zero_bytes, stream);

  const int tb = 256;
  fill_kernel<<<(E + tb - 1) / tb, tb, 0, stream>>>(src, dst, cnt, ell, E);
  dinv_kernel<<<(N + tb - 1) / tb, tb, 0, stream>>>(cnt, dinv, N);

  gemm_kernel<FIN><<<(N + 3) / 4, tb, 0, stream>>>(x, W1, bufA, N);
  conv_kernel<false><<<(N + 3) / 4, tb, 0, stream>>>(bufA, ell, cnt, dinv, b1, bufB, nullptr, N);
  gemm_kernel<HDIM><<<(N + 3) / 4, tb, 0, stream>>>(bufB, W2, bufA, N);
  conv_kernel<true><<<(N + 3) / 4, tb, 0, stream>>>(bufA, ell, cnt, dinv, b2, bufC, sumz, N);

  pos_kernel<<<(N + 3) / 4, tb, 0, stream>>>(ell, cnt, bufC, pos_sum, pos_cnt, N);
  finalize_kernel<<<1, 64, 0, stream>>>(sumz, pos_sum, pos_cnt, out, N);
}